// Round 1
// baseline (2633.813 us; speedup 1.0000x reference)
//
#include <hip/hip_runtime.h>
#include <math.h>

#define NN 325
#define BT 96

__device__ __forceinline__ float gelu_f(float x) {
    return 0.5f * x * (1.0f + erff(x * 0.70710678118654752f));
}

// ---------------------------------------------------------------------------
// Kernel 1: x = concat(X, STE) [.,128]; q/k/v = gelu(x @ W.T + b)  [.,64]
// One block per (bt, 32-row tile). LDS: x rows (stride 132) + transposed
// weight tile (stride 68, float4-aligned, conflict-light). 3 phases reuse ws.
// ---------------------------------------------------------------------------
__global__ __launch_bounds__(256) void qkv_kernel(
    const float* __restrict__ X, const float* __restrict__ STE,
    const float* __restrict__ W7, const float* __restrict__ b7,
    const float* __restrict__ W8, const float* __restrict__ b8,
    const float* __restrict__ W9, const float* __restrict__ b9,
    float* __restrict__ q, float* __restrict__ k, float* __restrict__ v)
{
    __shared__ float xs[32 * 132];
    __shared__ float ws[128 * 68];
    const int tid = threadIdx.x;
    const int bt  = blockIdx.y;
    const int r0  = blockIdx.x * 32;

    // stage x = concat(X, STE)
    for (int idx = tid; idx < 32 * 128; idx += 256) {
        int r = idx >> 7, i = idx & 127;
        int n = r0 + r;
        float val = 0.0f;
        if (n < NN) {
            val = (i < 64) ? X[(bt * NN + n) * 64 + i]
                           : STE[(bt * NN + n) * 64 + (i - 64)];
        }
        xs[r * 132 + i] = val;
    }

    const float* Wmat[3] = {W7, W8, W9};
    const float* bvec[3] = {b7, b8, b9};
    float*       outp[3] = {q, k, v};

    const int c4 = (tid & 15) * 4;   // 4 output cols
    const int rg = tid >> 4;         // rows rg and rg+16

    for (int p = 0; p < 3; ++p) {
        __syncthreads();
        const float* W = Wmat[p];
        for (int idx = tid; idx < 64 * 128; idx += 256) {
            int c = idx >> 7, i = idx & 127;
            ws[i * 68 + c] = W[idx];   // transposed store, bank stride 4
        }
        __syncthreads();

        float4 bias = *(const float4*)(bvec[p] + c4);
        float4 acc0 = bias, acc1 = bias;
        const float* x0p = xs + rg * 132;
        const float* x1p = xs + (rg + 16) * 132;
        #pragma unroll
        for (int i0 = 0; i0 < 128; i0 += 4) {
            float4 x0 = *(const float4*)(x0p + i0);
            float4 x1 = *(const float4*)(x1p + i0);
            #pragma unroll
            for (int u = 0; u < 4; ++u) {
                float4 w4 = *(const float4*)&ws[(i0 + u) * 68 + c4];
                float xa = (&x0.x)[u], xb = (&x1.x)[u];
                acc0.x += xa * w4.x; acc0.y += xa * w4.y;
                acc0.z += xa * w4.z; acc0.w += xa * w4.w;
                acc1.x += xb * w4.x; acc1.y += xb * w4.y;
                acc1.z += xb * w4.z; acc1.w += xb * w4.w;
            }
        }
        int n0 = r0 + rg, n1 = r0 + rg + 16;
        if (n0 < NN) {
            float4 g;
            g.x = gelu_f(acc0.x); g.y = gelu_f(acc0.y);
            g.z = gelu_f(acc0.z); g.w = gelu_f(acc0.w);
            *(float4*)&outp[p][(bt * NN + n0) * 64 + c4] = g;
        }
        if (n1 < NN) {
            float4 g;
            g.x = gelu_f(acc1.x); g.y = gelu_f(acc1.y);
            g.z = gelu_f(acc1.z); g.w = gelu_f(acc1.w);
            *(float4*)&outp[p][(bt * NN + n1) * 64 + c4] = g;
        }
    }
}

// ---------------------------------------------------------------------------
// Kernel 2: per (bt, head): scores = qk^T/sqrt(8), adj mask, softmax, PV.
// K,V stored transposed in LDS (KT[dd][m]) -> lane-per-m reads conflict-free.
// One wave per query row; butterfly shfl reductions over 64 lanes.
// ---------------------------------------------------------------------------
__global__ __launch_bounds__(256) void attn_kernel(
    const float* __restrict__ q, const float* __restrict__ k,
    const float* __restrict__ v, const int* __restrict__ adj,
    float* __restrict__ ao)
{
    __shared__ float Qs[NN * 8];
    __shared__ float KT[8 * NN];
    __shared__ float VT[8 * NN];
    const int tid = threadIdx.x;
    const int h = blockIdx.x, bt = blockIdx.y;
    const int base = (bt * NN) * 64 + h * 8;

    for (int idx = tid; idx < NN * 8; idx += 256) {
        int n = idx >> 3, dd = idx & 7;
        Qs[idx]          = q[base + n * 64 + dd];
        KT[dd * NN + n]  = k[base + n * 64 + dd];
        VT[dd * NN + n]  = v[base + n * 64 + dd];
    }
    __syncthreads();

    const int wave = tid >> 6, lane = tid & 63;
    for (int n = wave; n < NN; n += 4) {
        float qr[8];
        #pragma unroll
        for (int dd = 0; dd < 8; ++dd) qr[dd] = Qs[n * 8 + dd];
        const int* arow = adj + n * NN;

        float s[6];
        #pragma unroll
        for (int j = 0; j < 6; ++j) {
            int m = lane + j * 64;
            bool valid = (m < NN);
            int mc = valid ? m : 0;
            float acc = 0.0f;
            #pragma unroll
            for (int dd = 0; dd < 8; ++dd) acc += qr[dd] * KT[dd * NN + mc];
            acc *= 0.35355339059327373f;  // 1/sqrt(8)
            int a = valid ? arow[m] : 0;
            s[j] = valid ? ((a > 0) ? acc : -9.0e15f) : -3.0e38f;
        }

        float mx = s[0];
        #pragma unroll
        for (int j = 1; j < 6; ++j) mx = fmaxf(mx, s[j]);
        #pragma unroll
        for (int off = 32; off >= 1; off >>= 1)
            mx = fmaxf(mx, __shfl_xor(mx, off, 64));

        float p[6];
        float sum = 0.0f;
        #pragma unroll
        for (int j = 0; j < 6; ++j) { p[j] = __expf(s[j] - mx); sum += p[j]; }
        #pragma unroll
        for (int off = 32; off >= 1; off >>= 1)
            sum += __shfl_xor(sum, off, 64);
        float inv = 1.0f / sum;

        float acc[8] = {0.f,0.f,0.f,0.f,0.f,0.f,0.f,0.f};
        #pragma unroll
        for (int j = 0; j < 6; ++j) {
            int m = lane + j * 64;
            int mc = (m < NN) ? m : 0;   // p[j]==0 when invalid, VT[..0] finite
            float pj = p[j];
            #pragma unroll
            for (int dd = 0; dd < 8; ++dd) acc[dd] += pj * VT[dd * NN + mc];
        }
        #pragma unroll
        for (int dd = 0; dd < 8; ++dd) {
            #pragma unroll
            for (int off = 32; off >= 1; off >>= 1)
                acc[dd] += __shfl_xor(acc[dd], off, 64);
        }
        if (lane == 0) {
            #pragma unroll
            for (int dd = 0; dd < 8; ++dd)
                ao[base + n * 64 + dd] = acc[dd] * inv;
        }
    }
}

// ---------------------------------------------------------------------------
// Kernel 3: out = gelu(ao @ W10.T + b10) @ W11.T + b11.  16 rows/block,
// transposed weights with +1 pad (conflict-free), h staged in LDS.
// ---------------------------------------------------------------------------
__global__ __launch_bounds__(256) void proj_kernel(
    const float* __restrict__ ao,
    const float* __restrict__ W10, const float* __restrict__ b10,
    const float* __restrict__ W11, const float* __restrict__ b11,
    float* __restrict__ out)
{
    __shared__ float W10s[64 * 65];
    __shared__ float W11s[64 * 65];
    __shared__ float as_[16 * 64];
    __shared__ float hs[16 * 64];
    const int tid = threadIdx.x;
    const int rowbase = blockIdx.x * 16;

    for (int idx = tid; idx < 4096; idx += 256) {
        int c = idx >> 6, i = idx & 63;
        W10s[i * 65 + c] = W10[idx];
        W11s[i * 65 + c] = W11[idx];
    }
    for (int idx = tid; idx < 1024; idx += 256)
        as_[idx] = ao[rowbase * 64 + idx];
    __syncthreads();

    const int c = tid & 63, rg = tid >> 6;  // whole wave shares rg
    float bb = b10[c];
    float acc[4];
    #pragma unroll
    for (int rr = 0; rr < 4; ++rr) acc[rr] = bb;
    for (int i = 0; i < 64; ++i) {
        float w = W10s[i * 65 + c];
        #pragma unroll
        for (int rr = 0; rr < 4; ++rr)
            acc[rr] += as_[(rg * 4 + rr) * 64 + i] * w;
    }
    #pragma unroll
    for (int rr = 0; rr < 4; ++rr)
        hs[(rg * 4 + rr) * 64 + c] = gelu_f(acc[rr]);
    __syncthreads();

    float bb2 = b11[c];
    float acc2[4];
    #pragma unroll
    for (int rr = 0; rr < 4; ++rr) acc2[rr] = bb2;
    for (int i = 0; i < 64; ++i) {
        float w = W11s[i * 65 + c];
        #pragma unroll
        for (int rr = 0; rr < 4; ++rr)
            acc2[rr] += hs[(rg * 4 + rr) * 64 + i] * w;
    }
    #pragma unroll
    for (int rr = 0; rr < 4; ++rr)
        out[(rowbase + rg * 4 + rr) * 64 + c] = acc2[rr];
}

extern "C" void kernel_launch(void* const* d_in, const int* in_sizes, int n_in,
                              void* d_out, int out_size, void* d_ws, size_t ws_size,
                              hipStream_t stream) {
    const float* X   = (const float*)d_in[0];
    const float* STE = (const float*)d_in[1];
    const int*   adj = (const int*)d_in[2];
    const float* W7  = (const float*)d_in[3];
    const float* b7  = (const float*)d_in[4];
    const float* W8  = (const float*)d_in[5];
    const float* b8  = (const float*)d_in[6];
    const float* W9  = (const float*)d_in[7];
    const float* b9  = (const float*)d_in[8];
    const float* W10 = (const float*)d_in[9];
    const float* b10 = (const float*)d_in[10];
    const float* W11 = (const float*)d_in[11];
    const float* b11 = (const float*)d_in[12];

    float* ws = (float*)d_ws;
    const long S = (long)BT * NN * 64;  // 1,996,800 floats
    float* qb = ws;
    float* kb = ws + S;
    float* vb = ws + 2 * S;
    float* ab = ws + 3 * S;

    qkv_kernel<<<dim3(11, BT), 256, 0, stream>>>(X, STE, W7, b7, W8, b8, W9, b9,
                                                 qb, kb, vb);
    attn_kernel<<<dim3(8, BT), 256, 0, stream>>>(qb, kb, vb, adj, ab);
    proj_kernel<<<dim3(1950), 256, 0, stream>>>(ab, W10, b10, W11, b11,
                                                (float*)d_out);
}

// Round 2
// 352.407 us; speedup vs baseline: 7.4738x; 7.4738x over previous
//
#include <hip/hip_runtime.h>
#include <math.h>

#define NN 325
#define BT 96

__device__ __forceinline__ float gelu_f(float x) {
    return 0.5f * x * (1.0f + erff(x * 0.70710678118654752f));
}

// ---------------------------------------------------------------------------
// Kernel 1: x = concat(X, STE) [.,128]; q/k/v = gelu(x @ W.T + b)  [.,64]
// One block per (bt, 32-row tile). LDS: x rows (stride 132) + transposed
// weight tile (stride 68). Phases are explicit inlined calls (no pointer
// arrays -> no scratch); reduction loop unroll bounded to 4 (no spill).
// ---------------------------------------------------------------------------
__device__ __forceinline__ void qkv_phase(
    const float* __restrict__ W, const float* __restrict__ b,
    float* __restrict__ outp, const float* xs, float* ws,
    int tid, int bt, int r0)
{
    __syncthreads();
    for (int idx = tid; idx < 64 * 128; idx += 256) {
        int c = idx >> 7, i = idx & 127;
        ws[i * 68 + c] = W[idx];   // transposed store
    }
    __syncthreads();

    const int c4 = (tid & 15) * 4;   // 4 output cols
    const int rg = tid >> 4;         // rows rg and rg+16

    float4 bias = *(const float4*)(b + c4);
    float4 acc0 = bias, acc1 = bias;
    const float* x0p = xs + rg * 132;
    const float* x1p = xs + (rg + 16) * 132;
    #pragma unroll 4
    for (int i = 0; i < 128; ++i) {
        float xa = x0p[i], xb = x1p[i];
        float4 w4 = *(const float4*)&ws[i * 68 + c4];
        acc0.x = fmaf(xa, w4.x, acc0.x);
        acc0.y = fmaf(xa, w4.y, acc0.y);
        acc0.z = fmaf(xa, w4.z, acc0.z);
        acc0.w = fmaf(xa, w4.w, acc0.w);
        acc1.x = fmaf(xb, w4.x, acc1.x);
        acc1.y = fmaf(xb, w4.y, acc1.y);
        acc1.z = fmaf(xb, w4.z, acc1.z);
        acc1.w = fmaf(xb, w4.w, acc1.w);
    }
    int n0 = r0 + rg, n1 = r0 + rg + 16;
    if (n0 < NN) {
        float4 g;
        g.x = gelu_f(acc0.x); g.y = gelu_f(acc0.y);
        g.z = gelu_f(acc0.z); g.w = gelu_f(acc0.w);
        *(float4*)&outp[(bt * NN + n0) * 64 + c4] = g;
    }
    if (n1 < NN) {
        float4 g;
        g.x = gelu_f(acc1.x); g.y = gelu_f(acc1.y);
        g.z = gelu_f(acc1.z); g.w = gelu_f(acc1.w);
        *(float4*)&outp[(bt * NN + n1) * 64 + c4] = g;
    }
}

__global__ __launch_bounds__(256) void qkv_kernel(
    const float* __restrict__ X, const float* __restrict__ STE,
    const float* __restrict__ W7, const float* __restrict__ b7,
    const float* __restrict__ W8, const float* __restrict__ b8,
    const float* __restrict__ W9, const float* __restrict__ b9,
    float* __restrict__ q, float* __restrict__ k, float* __restrict__ v)
{
    __shared__ float xs[32 * 132];
    __shared__ float ws[128 * 68];
    const int tid = threadIdx.x;
    const int bt  = blockIdx.y;
    const int r0  = blockIdx.x * 32;

    // stage x = concat(X, STE)
    for (int idx = tid; idx < 32 * 128; idx += 256) {
        int r = idx >> 7, i = idx & 127;
        int n = r0 + r;
        float val = 0.0f;
        if (n < NN) {
            val = (i < 64) ? X[(bt * NN + n) * 64 + i]
                           : STE[(bt * NN + n) * 64 + (i - 64)];
        }
        xs[r * 132 + i] = val;
    }

    qkv_phase(W7, b7, q, xs, ws, tid, bt, r0);
    qkv_phase(W8, b8, k, xs, ws, tid, bt, r0);
    qkv_phase(W9, b9, v, xs, ws, tid, bt, r0);
}

// ---------------------------------------------------------------------------
// Kernel 2: per (bt, head): scores = qk^T/sqrt(8), adj mask, softmax, PV.
// K,V stored transposed in LDS (KT[dd][m]) -> lane-per-m reads conflict-free.
// One wave per query row; butterfly shfl reductions over 64 lanes.
// ---------------------------------------------------------------------------
__global__ __launch_bounds__(256) void attn_kernel(
    const float* __restrict__ q, const float* __restrict__ k,
    const float* __restrict__ v, const int* __restrict__ adj,
    float* __restrict__ ao)
{
    __shared__ float Qs[NN * 8];
    __shared__ float KT[8 * NN];
    __shared__ float VT[8 * NN];
    const int tid = threadIdx.x;
    const int h = blockIdx.x, bt = blockIdx.y;
    const int base = (bt * NN) * 64 + h * 8;

    for (int idx = tid; idx < NN * 8; idx += 256) {
        int n = idx >> 3, dd = idx & 7;
        Qs[idx]          = q[base + n * 64 + dd];
        KT[dd * NN + n]  = k[base + n * 64 + dd];
        VT[dd * NN + n]  = v[base + n * 64 + dd];
    }
    __syncthreads();

    const int wave = tid >> 6, lane = tid & 63;
    for (int n = wave; n < NN; n += 4) {
        float qr[8];
        #pragma unroll
        for (int dd = 0; dd < 8; ++dd) qr[dd] = Qs[n * 8 + dd];
        const int* arow = adj + n * NN;

        float s[6];
        #pragma unroll
        for (int j = 0; j < 6; ++j) {
            int m = lane + j * 64;
            bool valid = (m < NN);
            int mc = valid ? m : 0;
            float acc = 0.0f;
            #pragma unroll
            for (int dd = 0; dd < 8; ++dd)
                acc = fmaf(qr[dd], KT[dd * NN + mc], acc);
            acc *= 0.35355339059327373f;  // 1/sqrt(8)
            int a = valid ? arow[m] : 0;
            s[j] = valid ? ((a > 0) ? acc : -9.0e15f) : -3.0e38f;
        }

        float mx = s[0];
        #pragma unroll
        for (int j = 1; j < 6; ++j) mx = fmaxf(mx, s[j]);
        #pragma unroll
        for (int off = 32; off >= 1; off >>= 1)
            mx = fmaxf(mx, __shfl_xor(mx, off, 64));

        float p[6];
        float sum = 0.0f;
        #pragma unroll
        for (int j = 0; j < 6; ++j) { p[j] = __expf(s[j] - mx); sum += p[j]; }
        #pragma unroll
        for (int off = 32; off >= 1; off >>= 1)
            sum += __shfl_xor(sum, off, 64);
        float inv = 1.0f / sum;

        float acc[8] = {0.f,0.f,0.f,0.f,0.f,0.f,0.f,0.f};
        #pragma unroll
        for (int j = 0; j < 6; ++j) {
            int m = lane + j * 64;
            int mc = (m < NN) ? m : 0;   // p[j]==0 when invalid, VT[..0] finite
            float pj = p[j];
            #pragma unroll
            for (int dd = 0; dd < 8; ++dd)
                acc[dd] = fmaf(pj, VT[dd * NN + mc], acc[dd]);
        }
        #pragma unroll
        for (int dd = 0; dd < 8; ++dd) {
            #pragma unroll
            for (int off = 32; off >= 1; off >>= 1)
                acc[dd] += __shfl_xor(acc[dd], off, 64);
        }
        if (lane == 0) {
            #pragma unroll
            for (int dd = 0; dd < 8; ++dd)
                ao[base + n * 64 + dd] = acc[dd] * inv;
        }
    }
}

// ---------------------------------------------------------------------------
// Kernel 3: out = gelu(ao @ W10.T + b10) @ W11.T + b11.  16 rows/block,
// transposed weights with +1 pad (conflict-free), h staged in LDS.
// Reduction loops unroll-bounded to avoid spill.
// ---------------------------------------------------------------------------
__global__ __launch_bounds__(256) void proj_kernel(
    const float* __restrict__ ao,
    const float* __restrict__ W10, const float* __restrict__ b10,
    const float* __restrict__ W11, const float* __restrict__ b11,
    float* __restrict__ out)
{
    __shared__ float W10s[64 * 65];
    __shared__ float W11s[64 * 65];
    __shared__ float as_[16 * 64];
    __shared__ float hs[16 * 64];
    const int tid = threadIdx.x;
    const int rowbase = blockIdx.x * 16;

    for (int idx = tid; idx < 4096; idx += 256) {
        int c = idx >> 6, i = idx & 63;
        W10s[i * 65 + c] = W10[idx];
        W11s[i * 65 + c] = W11[idx];
    }
    for (int idx = tid; idx < 1024; idx += 256)
        as_[idx] = ao[rowbase * 64 + idx];
    __syncthreads();

    const int c = tid & 63, rg = tid >> 6;  // whole wave shares rg
    float bb = b10[c];
    float acc[4];
    #pragma unroll
    for (int rr = 0; rr < 4; ++rr) acc[rr] = bb;
    #pragma unroll 8
    for (int i = 0; i < 64; ++i) {
        float w = W10s[i * 65 + c];
        #pragma unroll
        for (int rr = 0; rr < 4; ++rr)
            acc[rr] = fmaf(as_[(rg * 4 + rr) * 64 + i], w, acc[rr]);
    }
    #pragma unroll
    for (int rr = 0; rr < 4; ++rr)
        hs[(rg * 4 + rr) * 64 + c] = gelu_f(acc[rr]);
    __syncthreads();

    float bb2 = b11[c];
    float acc2[4];
    #pragma unroll
    for (int rr = 0; rr < 4; ++rr) acc2[rr] = bb2;
    #pragma unroll 8
    for (int i = 0; i < 64; ++i) {
        float w = W11s[i * 65 + c];
        #pragma unroll
        for (int rr = 0; rr < 4; ++rr)
            acc2[rr] = fmaf(hs[(rg * 4 + rr) * 64 + i], w, acc2[rr]);
    }
    #pragma unroll
    for (int rr = 0; rr < 4; ++rr)
        out[(rowbase + rg * 4 + rr) * 64 + c] = acc2[rr];
}

extern "C" void kernel_launch(void* const* d_in, const int* in_sizes, int n_in,
                              void* d_out, int out_size, void* d_ws, size_t ws_size,
                              hipStream_t stream) {
    const float* X   = (const float*)d_in[0];
    const float* STE = (const float*)d_in[1];
    const int*   adj = (const int*)d_in[2];
    const float* W7  = (const float*)d_in[3];
    const float* b7  = (const float*)d_in[4];
    const float* W8  = (const float*)d_in[5];
    const float* b8  = (const float*)d_in[6];
    const float* W9  = (const float*)d_in[7];
    const float* b9  = (const float*)d_in[8];
    const float* W10 = (const float*)d_in[9];
    const float* b10 = (const float*)d_in[10];
    const float* W11 = (const float*)d_in[11];
    const float* b11 = (const float*)d_in[12];

    float* ws = (float*)d_ws;
    const long S = (long)BT * NN * 64;  // 1,996,800 floats
    float* qb = ws;
    float* kb = ws + S;
    float* vb = ws + 2 * S;
    float* ab = ws + 3 * S;

    qkv_kernel<<<dim3(11, BT), 256, 0, stream>>>(X, STE, W7, b7, W8, b8, W9, b9,
                                                 qb, kb, vb);
    attn_kernel<<<dim3(8, BT), 256, 0, stream>>>(qb, kb, vb, adj, ab);
    proj_kernel<<<dim3(1950), 256, 0, stream>>>(ab, W10, b10, W11, b11,
                                                (float*)d_out);
}